// Round 6
// baseline (178.366 us; speedup 1.0000x reference)
//
#include <hip/hip_runtime.h>
#include <cstdint>
#include <cstddef>

typedef unsigned short u16;
typedef __attribute__((ext_vector_type(8))) short s16x8;
typedef __attribute__((ext_vector_type(8))) u16 u16x8;
typedef __attribute__((ext_vector_type(4))) float f32x4;

#define DEV static __device__ __forceinline__
#define GPTR(p) (const __attribute__((address_space(1))) void*)(p)
#define LPTR(p) (__attribute__((address_space(3))) void*)(p)
#define SCHEDB __builtin_amdgcn_sched_barrier(0)
#define BAR __builtin_amdgcn_s_barrier()
#define SETP1 __builtin_amdgcn_s_setprio(1)
#define SETP0 __builtin_amdgcn_s_setprio(0)

DEV float b2f(u16 u) { union { unsigned i; float f; } c; c.i = ((unsigned)u) << 16; return c.f; }
DEV u16 f2b(float f) {
  union { float f; unsigned i; } c; c.f = f;
  unsigned r = (c.i + 0x7fffu + ((c.i >> 16) & 1u)) >> 16;
  return (u16)r;
}
DEV float sigm(float x) { return 1.0f / (1.0f + __expf(-x)); }

// ---------------------------------------------------------------------------
// Pack gate weights (f32 in) into concatenated bf16 [N,1536]:
//   WZR rows 0..1023    = [W_xz | W_hz | W_mz]
//   WZR rows 1024..2047 = [W_xr | W_hr | W_mr]
//   WH  rows 0..1023    = [W_xh | W_hh | W_mh]
// plus bf16 copy of W_gamma_h -> WGH [1024,256].
// ---------------------------------------------------------------------------
__global__ __launch_bounds__(256) void pack_w(
    const float* __restrict__ Wxz, const float* __restrict__ Whz, const float* __restrict__ Wmz,
    const float* __restrict__ Wxr, const float* __restrict__ Whr, const float* __restrict__ Wmr,
    const float* __restrict__ Wxh, const float* __restrict__ Whh, const float* __restrict__ Wmh,
    const float* __restrict__ Wgh,
    u16* __restrict__ WZR, u16* __restrict__ WH, u16* __restrict__ WGH)
{
  int t = blockIdx.x * 256 + threadIdx.x;
  const float* src;
  u16* dst;
  if (t < 589824) {
    int row = t / 192;
    int col = (t % 192) * 8;
    int rr = row & 1023;
    const float *wx, *wh, *wm;
    if (row < 1024)      { wx = Wxz; wh = Whz; wm = Wmz; }
    else if (row < 2048) { wx = Wxr; wh = Whr; wm = Wmr; }
    else                 { wx = Wxh; wh = Whh; wm = Wmh; }
    if (col < 256)       src = wx + rr * 256 + col;
    else if (col < 1280) src = wh + (size_t)rr * 1024 + (col - 256);
    else                 src = wm + rr * 256 + (col - 1280);
    dst = (row < 2048) ? (WZR + (size_t)row * 1536 + col)
                       : (WH + (size_t)(row - 2048) * 1536 + col);
  } else {
    int t2 = t - 589824;
    src = Wgh + t2 * 8;
    dst = WGH + t2 * 8;
  }
  f32x4 a = *(const f32x4*)src;
  f32x4 b = *(const f32x4*)(src + 4);
  u16x8 v;
#pragma unroll
  for (int j = 0; j < 4; ++j) { v[j] = f2b(a[j]); v[j + 4] = f2b(b[j]); }
  *(u16x8*)dst = v;
}

// ---------------------------------------------------------------------------
// Elementwise over [B,D]: gamma_x, imputation, x_hat -> X1/X2 cols 0..255 and
// 1280..1535 (m), bf16 delta copy, f32 x_last_obs_new.
// ---------------------------------------------------------------------------
__global__ __launch_bounds__(256) void elem_k(
    const float* __restrict__ x, const float* __restrict__ m, const float* __restrict__ delta,
    const float* __restrict__ xlo, const float* __restrict__ x_mean,
    const float* __restrict__ Wgx, const float* __restrict__ bgx,
    u16* __restrict__ X1, u16* __restrict__ X2, u16* __restrict__ Dbf,
    float* __restrict__ out_xlo)
{
  int t = blockIdx.x * 256 + threadIdx.x;
  int row = t >> 5;
  int col = (t & 31) * 8;
  size_t base = (size_t)row * 256 + col;
  u16x8 vxhat, vm16, vd16;
  f32x4 vlnew[2];
#pragma unroll
  for (int half = 0; half < 2; ++half) {
    f32x4 vx = *(const f32x4*)(x + base + half * 4);
    f32x4 vm = *(const f32x4*)(m + base + half * 4);
    f32x4 vd = *(const f32x4*)(delta + base + half * 4);
    f32x4 vl = *(const f32x4*)(xlo + base + half * 4);
    f32x4 vmean = *(const f32x4*)(x_mean + col + half * 4);
    f32x4 vwg = *(const f32x4*)(Wgx + col + half * 4);
    f32x4 vbg = *(const f32x4*)(bgx + col + half * 4);
#pragma unroll
    for (int j = 0; j < 4; ++j) {
      float mf = vm[j];
      float lnew = (mf > 0.5f) ? vx[j] : vl[j];
      vlnew[half][j] = lnew;
      float gx = __expf(-fmaxf(vd[j] * vwg[j] + vbg[j], 0.0f));
      float ximp = gx * lnew + (1.0f - gx) * vmean[j];
      float xhat = mf * vx[j] + (1.0f - mf) * ximp;
      vxhat[half * 4 + j] = f2b(xhat);
      vm16[half * 4 + j] = f2b(mf);
      vd16[half * 4 + j] = f2b(vd[j]);
    }
  }
  size_t r1536 = (size_t)row * 1536;
  *(u16x8*)(X1 + r1536 + col) = vxhat;
  *(u16x8*)(X2 + r1536 + col) = vxhat;
  *(u16x8*)(X1 + r1536 + 1280 + col) = vm16;
  *(u16x8*)(X2 + r1536 + 1280 + col) = vm16;
  *(u16x8*)(Dbf + base) = vd16;
  *(f32x4*)(out_xlo + base) = vlnew[0];
  *(f32x4*)(out_xlo + base + 4) = vlnew[1];
}

// ---------------------------------------------------------------------------
// 128x128-tile pipelined bf16 GEMM, 2 blocks/CU (cross-block TLP):
//   C[M,N] = A[M,K] @ W[N,K]^T.  BM=BN=128, BK=64, 4 waves (2Mx2N),
//   per-wave 64x64 (4x4 frags, 16 MFMA/phase).  LDS 64KB (dbuf x 2 k-half
//   slots x {A,B}) -> TWO co-resident blocks per CU; independent barrier
//   groups fill each other's per-phase stalls (m114 mechanism).
// Phase (2 per K-tile, ONE barrier per phase):
//   { ds_read 8 frags (slot published by prev BAR) ; stage 4 loads (unit
//     consumed 2 phases later) ; vmcnt(4) [drains unit staged 2 phases ago,
//     never 0 in steady state] ; BAR (publish) ; lgkmcnt(0) ; 16 MFMA }
// Slot safety: reads of slot S complete before this wave's lgkm0 -> before
// it reaches the NEXT phase's BAR -> restage of S (2 phases later) is issued
// only after ALL waves passed that BAR.  DMA-land vs read: unit staged in
// phase p is drained by vmcnt in p+1 and published by p+1's BAR before its
// reads in p+2.  Tail pair: vmcnt(0) at 3rd phase, no stages.
// Swizzle (0-conflict, verified r2-r5): 16B chunk ^= (row>>1)&3; linear LDS
// dest + inverse-swizzled global src + swizzled ds_read.  XCD-bijective
// block map (nwg%8==0): L = (d&7)*(nwg/8) + d>>3.
// EPI 0: h_decayed = exp(-relu(.+bgh)) * h      -> X1 cols 256..1279 (bf16)
// EPI 1: cols<1024: z=sigmoid -> Z ; cols>=1024: r*hdec -> X2 cols 256..1279
// EPI 2: h_new = (1-z)*hdec + z*tanh(.+bmh)     -> d_out (f32); A = X2
// ---------------------------------------------------------------------------
template<int EPI, int GXL>
__global__ __launch_bounds__(256, 2) void gemm_bt(
    const u16* __restrict__ A, int K, const u16* __restrict__ W,
    const float* __restrict__ bias0, const float* __restrict__ bias1,
    const float* __restrict__ auxf,  // EPI0: h (f32)
    const u16* __restrict__ auxb,    // EPI1/2: X1 (hdec source, bf16)
    const u16* __restrict__ aux2b,   // EPI2: Z (bf16)
    u16* __restrict__ out0b,         // EPI0: X1 ; EPI1: Z
    u16* __restrict__ out1b,         // EPI1: X2
    float* __restrict__ outf)        // EPI2: d_out h_new
{
  constexpr int GX = 1 << GXL;
  constexpr int SL = 128 * 32;             // elems per k-half slot (4096)
  __shared__ alignas(16) u16 As[4][SL];    // [buf*2+kh]
  __shared__ alignas(16) u16 Bs[4][SL];

  const int tid = threadIdx.x;
  const int lane = tid & 63;
  const int wave = tid >> 6;               // 0..3
  const int wr = wave >> 1, wc = wave & 1;

  // bijective XCD swizzle: nwg/8 consecutive logical blocks per XCD
  const int d = blockIdx.x;
  const int q = (int)gridDim.x >> 3;
  const int L = (d & 7) * q + (d >> 3);
  const int brow = (L >> GXL) * 128;
  const int bcol = (L & (GX - 1)) * 128;
  const int NT = K / 64;

  const int lr = lane & 15, g4 = lane >> 4;
  const int rc = (g4 ^ ((lr >> 1) & 3)) * 8;            // swizzled read chunk
  const int sr4 = lane >> 2;                            // staging row in 16-blk
  const int scs = ((lane & 3) ^ ((lane >> 3) & 3)) * 8; // inv-swizzled src col

  f32x4 acc[4][4];
#pragma unroll
  for (int i = 0; i < 4; ++i)
#pragma unroll
    for (int j = 0; j < 4; ++j) { f32x4 z0 = {0.f, 0.f, 0.f, 0.f}; acc[i][j] = z0; }

  // per-thread staging pointers (element units, k=0 of current pair)
  const u16* aP0 = A + (size_t)(brow + wave * 16 + sr4) * K + scs;
  const u16* aP1 = aP0 + (size_t)64 * K;
  const u16* bP0 = W + (size_t)(bcol + wave * 16 + sr4) * K + scs;
  const u16* bP1 = bP0 + (size_t)64 * K;
  u16* ldsA = &As[0][0] + wave * 512;
  u16* ldsB = &Bs[0][0] + wave * 512;
  const u16* rdA = &As[0][0] + (wr * 64 + lr) * 32 + rc;
  const u16* rdB = &Bs[0][0] + (wc * 64 + lr) * 32 + rc;

  auto STAGE = [&](int slot, int koff) {
    __builtin_amdgcn_global_load_lds(GPTR(aP0 + koff), LPTR(ldsA + slot * SL), 16, 0, 0);
    __builtin_amdgcn_global_load_lds(GPTR(aP1 + koff), LPTR(ldsA + slot * SL + 2048), 16, 0, 0);
    __builtin_amdgcn_global_load_lds(GPTR(bP0 + koff), LPTR(ldsB + slot * SL), 16, 0, 0);
    __builtin_amdgcn_global_load_lds(GPTR(bP1 + koff), LPTR(ldsB + slot * SL + 2048), 16, 0, 0);
  };

  // phase: reads(slotR) | stage(slotS) | vmcnt | BAR | lgkm0 | 16 MFMA
  auto PHASE = [&](int slotR, int slotS, int koff, int stg, int vm) {
    s16x8 af[4], bf[4];
    const u16* pA = rdA + slotR * SL;
    const u16* pB = rdB + slotR * SL;
#pragma unroll
    for (int i = 0; i < 4; ++i) af[i] = *(const s16x8*)(pA + i * 512);
#pragma unroll
    for (int j = 0; j < 4; ++j) bf[j] = *(const s16x8*)(pB + j * 512);
    if (stg) STAGE(slotS, koff);
    SCHEDB;
    if (vm == 4) asm volatile("s_waitcnt vmcnt(4)" ::: "memory");
    else if (vm == 0) asm volatile("s_waitcnt vmcnt(0)" ::: "memory");
    BAR;
    asm volatile("s_waitcnt lgkmcnt(0)" ::: "memory");
    SCHEDB;
    SETP1;
#pragma unroll
    for (int i = 0; i < 4; ++i)
#pragma unroll
      for (int j = 0; j < 4; ++j)
        acc[i][j] = __builtin_amdgcn_mfma_f32_16x16x32_bf16(af[i], bf[j], acc[i][j], 0, 0, 0);
    SETP0;
  };

  // prologue: stage U(0,k0)->slot0, U(0,k1)->slot1; drain slot0; publish
  STAGE(0, 0);
  STAGE(1, 32);
  asm volatile("s_waitcnt vmcnt(4)" ::: "memory");
  BAR;

  // main: 2 tiles per iteration, compile-time slots/offsets; NT is even
  for (int kt = 0; kt < NT - 2; kt += 2) {
    PHASE(0, 2, 64, 1, 4);    // t: k0   | stage (t+1,k0)
    PHASE(1, 3, 96, 1, 4);    // t: k1   | stage (t+1,k1)
    PHASE(2, 0, 128, 1, 4);   // t+1: k0 | stage (t+2,k0)
    PHASE(3, 1, 160, 1, 4);   // t+1: k1 | stage (t+2,k1)
    aP0 += 128; aP1 += 128; bP0 += 128; bP1 += 128;
  }
  // tail pair (tiles NT-2, NT-1): stage only tile NT-1
  PHASE(0, 2, 64, 1, 4);
  PHASE(1, 3, 96, 1, 4);
  PHASE(2, 0, 0, 0, 0);       // drain last stages for slot3
  PHASE(3, 0, 0, 0, -1);

  // epilogue: C/D layout col=lane&15, row=(lane>>4)*4+q  [verified m89/m91]
  const int row0 = brow + wr * 64 + g4 * 4;
  const int col0 = bcol + wc * 64 + lr;
#pragma unroll
  for (int i = 0; i < 4; ++i) {
#pragma unroll
    for (int j = 0; j < 4; ++j) {
      int c_ = col0 + j * 16;
#pragma unroll
      for (int qq = 0; qq < 4; ++qq) {
        int r_ = row0 + i * 16 + qq;
        float v = acc[i][j][qq];
        if constexpr (EPI == 0) {
          float p = v + bias0[c_];
          float gh = __expf(-fmaxf(p, 0.0f));
          float hd = gh * auxf[(size_t)r_ * 1024 + c_];
          out0b[(size_t)r_ * 1536 + 256 + c_] = f2b(hd);
        } else if constexpr (EPI == 1) {
          if (c_ < 1024) {
            out0b[(size_t)r_ * 1024 + c_] = f2b(sigm(v + bias0[c_]));
          } else {
            int jc = c_ - 1024;
            float rg = sigm(v + bias1[jc]);
            float hd = b2f(auxb[(size_t)r_ * 1536 + 256 + jc]);
            out1b[(size_t)r_ * 1536 + 256 + jc] = f2b(rg * hd);
          }
        } else {
          float ht = tanhf(v + bias0[c_]);
          float zz = b2f(aux2b[(size_t)r_ * 1024 + c_]);
          float hd = b2f(auxb[(size_t)r_ * 1536 + 256 + c_]);
          outf[(size_t)r_ * 1024 + c_] = (1.0f - zz) * hd + zz * ht;
        }
      }
    }
  }
}

// ---------------------------------------------------------------------------
extern "C" void kernel_launch(void* const* d_in, const int* in_sizes, int n_in,
                              void* d_out, int out_size, void* d_ws, size_t ws_size,
                              hipStream_t stream)
{
  const float* x     = (const float*)d_in[0];
  const float* m     = (const float*)d_in[1];
  const float* delta = (const float*)d_in[2];
  const float* h     = (const float*)d_in[3];
  const float* xlo   = (const float*)d_in[4];
  const float* xmean = (const float*)d_in[5];
  const float* Wgx   = (const float*)d_in[6];
  const float* bgx   = (const float*)d_in[7];
  const float* Wgh   = (const float*)d_in[8];
  const float* bgh   = (const float*)d_in[9];
  const float* Wxz   = (const float*)d_in[10];
  const float* Whz   = (const float*)d_in[11];
  const float* Wmz   = (const float*)d_in[12];
  const float* bmz   = (const float*)d_in[13];
  const float* Wxr   = (const float*)d_in[14];
  const float* Whr   = (const float*)d_in[15];
  const float* Wmr   = (const float*)d_in[16];
  const float* bmr   = (const float*)d_in[17];
  const float* Wxh   = (const float*)d_in[18];
  const float* Whh   = (const float*)d_in[19];
  const float* Wmh   = (const float*)d_in[20];
  const float* bmh   = (const float*)d_in[21];

  // workspace (bf16): X1[8192,1536] X2[8192,1536] Z[8192,1024]
  //   WZR[2048,1536] WH[1024,1536] Dbf[8192,256] WGH[1024,256]  ~81.3MB
  u16* X1  = (u16*)d_ws;
  u16* X2  = X1 + (size_t)8192 * 1536;
  u16* Z   = X2 + (size_t)8192 * 1536;
  u16* WZR = Z  + (size_t)8192 * 1024;
  u16* WH  = WZR + (size_t)2048 * 1536;
  u16* Dbf = WH + (size_t)1024 * 1536;
  u16* WGH = Dbf + (size_t)8192 * 256;

  float* out_h   = (float*)d_out;
  float* out_xlo = out_h + (size_t)8192 * 1024;

  pack_w<<<2432, 256, 0, stream>>>(Wxz, Whz, Wmz, Wxr, Whr, Wmr, Wxh, Whh, Wmh, Wgh, WZR, WH, WGH);
  elem_k<<<1024, 256, 0, stream>>>(x, m, delta, xlo, xmean, Wgx, bgx, X1, X2, Dbf, out_xlo);
  // GEMM A: gamma_h -> h_decayed into X1[:,256:1280]   (M=8192,N=1024,K=256)
  gemm_bt<0, 3><<<512, 256, 0, stream>>>(
      Dbf, 256, WGH, bgh, nullptr, h, nullptr, nullptr, X1, nullptr, nullptr);
  // GEMM B: z -> Z ; r*h_decayed -> X2[:,256:1280]     (M=8192,N=2048,K=1536)
  gemm_bt<1, 4><<<1024, 256, 0, stream>>>(
      X1, 1536, WZR, bmz, bmr, nullptr, X1, nullptr, Z, X2, nullptr);
  // GEMM C: h_tilde + final blend -> h_new (f32)       (M=8192,N=1024,K=1536)
  gemm_bt<2, 3><<<512, 256, 0, stream>>>(
      X2, 1536, WH, bmh, nullptr, nullptr, X1, Z, nullptr, nullptr, out_h);
}

// Round 7
// 159.832 us; speedup vs baseline: 1.1160x; 1.1160x over previous
//
#include <hip/hip_runtime.h>
#include <cstdint>
#include <cstddef>

typedef unsigned short u16;
typedef __attribute__((ext_vector_type(8))) short s16x8;
typedef __attribute__((ext_vector_type(8))) u16 u16x8;
typedef __attribute__((ext_vector_type(4))) float f32x4;

#define DEV static __device__ __forceinline__
#define GPTR(p) (const __attribute__((address_space(1))) void*)(p)
#define LPTR(p) (__attribute__((address_space(3))) void*)(p)
#define SCHEDB __builtin_amdgcn_sched_barrier(0)
#define BAR __builtin_amdgcn_s_barrier()
#define SETP1 __builtin_amdgcn_s_setprio(1)
#define SETP0 __builtin_amdgcn_s_setprio(0)

DEV float b2f(u16 u) { union { unsigned i; float f; } c; c.i = ((unsigned)u) << 16; return c.f; }
DEV u16 f2b(float f) {
  union { float f; unsigned i; } c; c.f = f;
  unsigned r = (c.i + 0x7fffu + ((c.i >> 16) & 1u)) >> 16;
  return (u16)r;
}
DEV float sigm(float x) { return 1.0f / (1.0f + __expf(-x)); }

// ---------------------------------------------------------------------------
// Pack gate weights (f32 in) into concatenated bf16 [N,1536]:
//   WZR rows 0..1023    = [W_xz | W_hz | W_mz]
//   WZR rows 1024..2047 = [W_xr | W_hr | W_mr]
//   WH  rows 0..1023    = [W_xh | W_hh | W_mh]
// plus bf16 copy of W_gamma_h -> WGH [1024,256].
// ---------------------------------------------------------------------------
__global__ __launch_bounds__(256) void pack_w(
    const float* __restrict__ Wxz, const float* __restrict__ Whz, const float* __restrict__ Wmz,
    const float* __restrict__ Wxr, const float* __restrict__ Whr, const float* __restrict__ Wmr,
    const float* __restrict__ Wxh, const float* __restrict__ Whh, const float* __restrict__ Wmh,
    const float* __restrict__ Wgh,
    u16* __restrict__ WZR, u16* __restrict__ WH, u16* __restrict__ WGH)
{
  int t = blockIdx.x * 256 + threadIdx.x;
  const float* src;
  u16* dst;
  if (t < 589824) {
    int row = t / 192;
    int col = (t % 192) * 8;
    int rr = row & 1023;
    const float *wx, *wh, *wm;
    if (row < 1024)      { wx = Wxz; wh = Whz; wm = Wmz; }
    else if (row < 2048) { wx = Wxr; wh = Whr; wm = Wmr; }
    else                 { wx = Wxh; wh = Whh; wm = Wmh; }
    if (col < 256)       src = wx + rr * 256 + col;
    else if (col < 1280) src = wh + (size_t)rr * 1024 + (col - 256);
    else                 src = wm + rr * 256 + (col - 1280);
    dst = (row < 2048) ? (WZR + (size_t)row * 1536 + col)
                       : (WH + (size_t)(row - 2048) * 1536 + col);
  } else {
    int t2 = t - 589824;
    src = Wgh + t2 * 8;
    dst = WGH + t2 * 8;
  }
  f32x4 a = *(const f32x4*)src;
  f32x4 b = *(const f32x4*)(src + 4);
  u16x8 v;
#pragma unroll
  for (int j = 0; j < 4; ++j) { v[j] = f2b(a[j]); v[j + 4] = f2b(b[j]); }
  *(u16x8*)dst = v;
}

// ---------------------------------------------------------------------------
// Elementwise over [B,D]: gamma_x, imputation, x_hat -> X1/X2 cols 0..255 and
// 1280..1535 (m), bf16 delta copy, f32 x_last_obs_new.
// ---------------------------------------------------------------------------
__global__ __launch_bounds__(256) void elem_k(
    const float* __restrict__ x, const float* __restrict__ m, const float* __restrict__ delta,
    const float* __restrict__ xlo, const float* __restrict__ x_mean,
    const float* __restrict__ Wgx, const float* __restrict__ bgx,
    u16* __restrict__ X1, u16* __restrict__ X2, u16* __restrict__ Dbf,
    float* __restrict__ out_xlo)
{
  int t = blockIdx.x * 256 + threadIdx.x;
  int row = t >> 5;
  int col = (t & 31) * 8;
  size_t base = (size_t)row * 256 + col;
  u16x8 vxhat, vm16, vd16;
  f32x4 vlnew[2];
#pragma unroll
  for (int half = 0; half < 2; ++half) {
    f32x4 vx = *(const f32x4*)(x + base + half * 4);
    f32x4 vm = *(const f32x4*)(m + base + half * 4);
    f32x4 vd = *(const f32x4*)(delta + base + half * 4);
    f32x4 vl = *(const f32x4*)(xlo + base + half * 4);
    f32x4 vmean = *(const f32x4*)(x_mean + col + half * 4);
    f32x4 vwg = *(const f32x4*)(Wgx + col + half * 4);
    f32x4 vbg = *(const f32x4*)(bgx + col + half * 4);
#pragma unroll
    for (int j = 0; j < 4; ++j) {
      float mf = vm[j];
      float lnew = (mf > 0.5f) ? vx[j] : vl[j];
      vlnew[half][j] = lnew;
      float gx = __expf(-fmaxf(vd[j] * vwg[j] + vbg[j], 0.0f));
      float ximp = gx * lnew + (1.0f - gx) * vmean[j];
      float xhat = mf * vx[j] + (1.0f - mf) * ximp;
      vxhat[half * 4 + j] = f2b(xhat);
      vm16[half * 4 + j] = f2b(mf);
      vd16[half * 4 + j] = f2b(vd[j]);
    }
  }
  size_t r1536 = (size_t)row * 1536;
  *(u16x8*)(X1 + r1536 + col) = vxhat;
  *(u16x8*)(X2 + r1536 + col) = vxhat;
  *(u16x8*)(X1 + r1536 + 1280 + col) = vm16;
  *(u16x8*)(X2 + r1536 + 1280 + col) = vm16;
  *(u16x8*)(Dbf + base) = vd16;
  *(f32x4*)(out_xlo + base) = vlnew[0];
  *(f32x4*)(out_xlo + base + 4) = vlnew[1];
}

// ---------------------------------------------------------------------------
// 128x128-tile pipelined bf16 GEMM, 8 waves x 512thr, 2 blocks/CU:
//   C[M,N] = A[M,K] @ W[N,K]^T.  BM=BN=128, BK=64, wave grid 2M x 4N,
//   per-wave 64x32 (4x2 frags, 8 MFMA/phase).  LDS 64KB (4-slot ring x
//   {A,B}, slot = one 128x32 k-half) -> TWO co-resident 8-wave blocks/CU
//   = 16 waves/CU = 4 waves/SIMD in two INDEPENDENT barrier groups:
//   block Y's MFMA fills block X's per-phase stall (m114 mechanism).
//   Per-SIMD MFMA density unchanged vs r5 (4 waves x 8 = 32 MFMA/phase).
// Phase (2 per K-tile, ONE barrier): { ds_read 6 frags (slot published by
//   prev BAR) ; stage unit u+2 (1 A-load + 1 B-load per thread) ; vmcnt(2)
//   [drains unit u+1, never 0 in steady state] ; BAR ; lgkm0 ; 8 MFMA }.
// Ring ledger: phase u consumes slot u&3 (staged at u-2, drained at u-1,
//   published by u-1's BAR).  Restage of slot s at phase s+2: its reads
//   retired at phase s's lgkm0, certified by s's trailing... by phase s+1's
//   BAR which all waves pass before any wave issues phase s+2's stage.
//   Prologue: 4 loads, vmcnt(2).  Tail: vmcnt(0) at 3rd-to-last phase.
// Swizzle (0-conflict, verified r2-r6): 16B chunk ^= (row>>1)&3; linear LDS
//   dest (glds lane-linear: wave*1024B + lane*16B) + inverse-swizzled global
//   src + swizzled ds_read.  XCD-bijective 1D map (nwg%8==0).
// EPI 0: h_decayed = exp(-relu(.+bgh)) * h      -> X1 cols 256..1279 (bf16)
// EPI 1: cols<1024: z=sigmoid -> Z ; cols>=1024: r*hdec -> X2 cols 256..1279
// EPI 2: h_new = (1-z)*hdec + z*tanh(.+bmh)     -> d_out (f32); A = X2
// ---------------------------------------------------------------------------
template<int EPI, int GXL>
__global__ __launch_bounds__(512, 4) void gemm_bt(
    const u16* __restrict__ A, int K, const u16* __restrict__ W,
    const float* __restrict__ bias0, const float* __restrict__ bias1,
    const float* __restrict__ auxf,  // EPI0: h (f32)
    const u16* __restrict__ auxb,    // EPI1/2: X1 (hdec source, bf16)
    const u16* __restrict__ aux2b,   // EPI2: Z (bf16)
    u16* __restrict__ out0b,         // EPI0: X1 ; EPI1: Z
    u16* __restrict__ out1b,         // EPI1: X2
    float* __restrict__ outf)        // EPI2: d_out h_new
{
  constexpr int GX = 1 << GXL;
  constexpr int SL = 128 * 32;             // elems per k-half slot (8KB)
  __shared__ alignas(16) u16 As[4][SL];
  __shared__ alignas(16) u16 Bs[4][SL];

  const int tid = threadIdx.x;
  const int lane = tid & 63;
  const int wave = tid >> 6;               // 0..7
  const int wr = wave >> 2, wc = wave & 3; // 2M x 4N

  // bijective XCD swizzle: nwg/8 consecutive logical blocks per XCD
  const int d = blockIdx.x;
  const int q = (int)gridDim.x >> 3;
  const int L = (d & 7) * q + (d >> 3);
  const int brow = (L >> GXL) * 128;
  const int bcol = (L & (GX - 1)) * 128;
  const int NT = K / 64;

  const int lr = lane & 15, g4 = lane >> 4;
  const int rc = (g4 ^ ((lr >> 1) & 3)) * 8;            // swizzled read chunk
  const int srow = lane >> 2;                           // staging row (0..15)
  const int scs = ((lane & 3) ^ ((srow >> 1) & 3)) * 8; // inv-swizzled src col

  f32x4 acc[4][2];
#pragma unroll
  for (int i = 0; i < 4; ++i)
#pragma unroll
    for (int j = 0; j < 2; ++j) { f32x4 z0 = {0.f, 0.f, 0.f, 0.f}; acc[i][j] = z0; }

  // per-thread staging pointers (element units, k=0 of current tile pair)
  const u16* aP = A + (size_t)(brow + wave * 16 + srow) * K + scs;
  const u16* bP = W + (size_t)(bcol + wave * 16 + srow) * K + scs;
  u16* ldsA = &As[0][0] + wave * 512;      // glds writes lane-linear 16B/lane
  u16* ldsB = &Bs[0][0] + wave * 512;
  const u16* rdA = &As[0][0] + (wr * 64 + lr) * 32 + rc;
  const u16* rdB = &Bs[0][0] + (wc * 32 + lr) * 32 + rc;

  auto STAGE = [&](int slot, int koff) {
    __builtin_amdgcn_global_load_lds(GPTR(aP + koff), LPTR(ldsA + slot * SL), 16, 0, 0);
    __builtin_amdgcn_global_load_lds(GPTR(bP + koff), LPTR(ldsB + slot * SL), 16, 0, 0);
  };

  // phase: reads(slotR) | stage(slotS) | vmcnt | BAR | lgkm0 | 8 MFMA
  auto PHASE = [&](int slotR, int slotS, int koff, int stg, int vm) {
    s16x8 af[4], bf[2];
    const u16* pA = rdA + slotR * SL;
    const u16* pB = rdB + slotR * SL;
#pragma unroll
    for (int i = 0; i < 4; ++i) af[i] = *(const s16x8*)(pA + i * 512);
#pragma unroll
    for (int j = 0; j < 2; ++j) bf[j] = *(const s16x8*)(pB + j * 512);
    if (stg) STAGE(slotS, koff);
    SCHEDB;
    if (vm == 2) asm volatile("s_waitcnt vmcnt(2)" ::: "memory");
    else if (vm == 0) asm volatile("s_waitcnt vmcnt(0)" ::: "memory");
    BAR;
    asm volatile("s_waitcnt lgkmcnt(0)" ::: "memory");
    SCHEDB;
    SETP1;
#pragma unroll
    for (int i = 0; i < 4; ++i)
#pragma unroll
      for (int j = 0; j < 2; ++j)
        acc[i][j] = __builtin_amdgcn_mfma_f32_16x16x32_bf16(af[i], bf[j], acc[i][j], 0, 0, 0);
    SETP0;
  };

  // prologue: stage units 0,1 -> slots 0,1; drain unit 0; publish
  STAGE(0, 0);
  STAGE(1, 32);
  asm volatile("s_waitcnt vmcnt(2)" ::: "memory");
  BAR;

  // main: 2 K-tiles (4 phases) per iteration, compile-time slots/offsets
  for (int kt = 0; kt < NT - 2; kt += 2) {
    PHASE(0, 2, 64, 1, 2);    // u: t,k0   | stage t+1,k0
    PHASE(1, 3, 96, 1, 2);    // u: t,k1   | stage t+1,k1
    PHASE(2, 0, 128, 1, 2);   // u: t+1,k0 | stage t+2,k0
    PHASE(3, 1, 160, 1, 2);   // u: t+1,k1 | stage t+2,k1
    aP += 128; bP += 128;
  }
  // tail pair (tiles NT-2, NT-1): stage only tile NT-1, then drain
  PHASE(0, 2, 64, 1, 2);
  PHASE(1, 3, 96, 1, 2);
  PHASE(2, 0, 0, 0, 0);
  PHASE(3, 0, 0, 0, -1);

  // epilogue: C/D layout col=lane&15, row=(lane>>4)*4+q  [verified m89/m91]
  const int row0 = brow + wr * 64 + g4 * 4;
  const int col0 = bcol + wc * 32 + lr;
#pragma unroll
  for (int i = 0; i < 4; ++i) {
#pragma unroll
    for (int j = 0; j < 2; ++j) {
      int c_ = col0 + j * 16;
#pragma unroll
      for (int qq = 0; qq < 4; ++qq) {
        int r_ = row0 + i * 16 + qq;
        float v = acc[i][j][qq];
        if constexpr (EPI == 0) {
          float p = v + bias0[c_];
          float gh = __expf(-fmaxf(p, 0.0f));
          float hd = gh * auxf[(size_t)r_ * 1024 + c_];
          out0b[(size_t)r_ * 1536 + 256 + c_] = f2b(hd);
        } else if constexpr (EPI == 1) {
          if (c_ < 1024) {
            out0b[(size_t)r_ * 1024 + c_] = f2b(sigm(v + bias0[c_]));
          } else {
            int jc = c_ - 1024;
            float rg = sigm(v + bias1[jc]);
            float hd = b2f(auxb[(size_t)r_ * 1536 + 256 + jc]);
            out1b[(size_t)r_ * 1536 + 256 + jc] = f2b(rg * hd);
          }
        } else {
          float ht = tanhf(v + bias0[c_]);
          float zz = b2f(aux2b[(size_t)r_ * 1024 + c_]);
          float hd = b2f(auxb[(size_t)r_ * 1536 + 256 + c_]);
          outf[(size_t)r_ * 1024 + c_] = (1.0f - zz) * hd + zz * ht;
        }
      }
    }
  }
}

// ---------------------------------------------------------------------------
extern "C" void kernel_launch(void* const* d_in, const int* in_sizes, int n_in,
                              void* d_out, int out_size, void* d_ws, size_t ws_size,
                              hipStream_t stream)
{
  const float* x     = (const float*)d_in[0];
  const float* m     = (const float*)d_in[1];
  const float* delta = (const float*)d_in[2];
  const float* h     = (const float*)d_in[3];
  const float* xlo   = (const float*)d_in[4];
  const float* xmean = (const float*)d_in[5];
  const float* Wgx   = (const float*)d_in[6];
  const float* bgx   = (const float*)d_in[7];
  const float* Wgh   = (const float*)d_in[8];
  const float* bgh   = (const float*)d_in[9];
  const float* Wxz   = (const float*)d_in[10];
  const float* Whz   = (const float*)d_in[11];
  const float* Wmz   = (const float*)d_in[12];
  const float* bmz   = (const float*)d_in[13];
  const float* Wxr   = (const float*)d_in[14];
  const float* Whr   = (const float*)d_in[15];
  const float* Wmr   = (const float*)d_in[16];
  const float* bmr   = (const float*)d_in[17];
  const float* Wxh   = (const float*)d_in[18];
  const float* Whh   = (const float*)d_in[19];
  const float* Wmh   = (const float*)d_in[20];
  const float* bmh   = (const float*)d_in[21];

  // workspace (bf16): X1[8192,1536] X2[8192,1536] Z[8192,1024]
  //   WZR[2048,1536] WH[1024,1536] Dbf[8192,256] WGH[1024,256]  ~81.3MB
  u16* X1  = (u16*)d_ws;
  u16* X2  = X1 + (size_t)8192 * 1536;
  u16* Z   = X2 + (size_t)8192 * 1536;
  u16* WZR = Z  + (size_t)8192 * 1024;
  u16* WH  = WZR + (size_t)2048 * 1536;
  u16* Dbf = WH + (size_t)1024 * 1536;
  u16* WGH = Dbf + (size_t)8192 * 256;

  float* out_h   = (float*)d_out;
  float* out_xlo = out_h + (size_t)8192 * 1024;

  pack_w<<<2432, 256, 0, stream>>>(Wxz, Whz, Wmz, Wxr, Whr, Wmr, Wxh, Whh, Wmh, Wgh, WZR, WH, WGH);
  elem_k<<<1024, 256, 0, stream>>>(x, m, delta, xlo, xmean, Wgx, bgx, X1, X2, Dbf, out_xlo);
  // GEMM A: gamma_h -> h_decayed into X1[:,256:1280]   (M=8192,N=1024,K=256)
  gemm_bt<0, 3><<<512, 512, 0, stream>>>(
      Dbf, 256, WGH, bgh, nullptr, h, nullptr, nullptr, X1, nullptr, nullptr);
  // GEMM B: z -> Z ; r*h_decayed -> X2[:,256:1280]     (M=8192,N=2048,K=1536)
  gemm_bt<1, 4><<<1024, 512, 0, stream>>>(
      X1, 1536, WZR, bmz, bmr, nullptr, X1, nullptr, Z, X2, nullptr);
  // GEMM C: h_tilde + final blend -> h_new (f32)       (M=8192,N=1024,K=1536)
  gemm_bt<2, 3><<<512, 512, 0, stream>>>(
      X2, 1536, WH, bmh, nullptr, nullptr, X1, Z, nullptr, nullptr, out_h);
}

// Round 8
// 153.483 us; speedup vs baseline: 1.1621x; 1.0414x over previous
//
#include <hip/hip_runtime.h>
#include <cstdint>
#include <cstddef>

typedef unsigned short u16;
typedef __attribute__((ext_vector_type(8))) short s16x8;
typedef __attribute__((ext_vector_type(8))) u16 u16x8;
typedef __attribute__((ext_vector_type(4))) float f32x4;

#define DEV static __device__ __forceinline__
#define GPTR(p) (const __attribute__((address_space(1))) void*)(p)
#define LPTR(p) (__attribute__((address_space(3))) void*)(p)
#define SCHEDB __builtin_amdgcn_sched_barrier(0)
#define BAR __builtin_amdgcn_s_barrier()
#define SETP1 __builtin_amdgcn_s_setprio(1)
#define SETP0 __builtin_amdgcn_s_setprio(0)

DEV float b2f(u16 u) { union { unsigned i; float f; } c; c.i = ((unsigned)u) << 16; return c.f; }
DEV u16 f2b(float f) {
  union { float f; unsigned i; } c; c.f = f;
  unsigned r = (c.i + 0x7fffu + ((c.i >> 16) & 1u)) >> 16;
  return (u16)r;
}
DEV float sigm(float x) { return 1.0f / (1.0f + __expf(-x)); }

// ---------------------------------------------------------------------------
// Pack gate weights (f32 in) into concatenated bf16 [N,1536]:
//   WZR rows 0..1023    = [W_xz | W_hz | W_mz]
//   WZR rows 1024..2047 = [W_xr | W_hr | W_mr]
//   WH  rows 0..1023    = [W_xh | W_hh | W_mh]
// plus bf16 copy of W_gamma_h -> WGH [1024,256].
// ---------------------------------------------------------------------------
__global__ __launch_bounds__(256) void pack_w(
    const float* __restrict__ Wxz, const float* __restrict__ Whz, const float* __restrict__ Wmz,
    const float* __restrict__ Wxr, const float* __restrict__ Whr, const float* __restrict__ Wmr,
    const float* __restrict__ Wxh, const float* __restrict__ Whh, const float* __restrict__ Wmh,
    const float* __restrict__ Wgh,
    u16* __restrict__ WZR, u16* __restrict__ WH, u16* __restrict__ WGH)
{
  int t = blockIdx.x * 256 + threadIdx.x;
  const float* src;
  u16* dst;
  if (t < 589824) {
    int row = t / 192;
    int col = (t % 192) * 8;
    int rr = row & 1023;
    const float *wx, *wh, *wm;
    if (row < 1024)      { wx = Wxz; wh = Whz; wm = Wmz; }
    else if (row < 2048) { wx = Wxr; wh = Whr; wm = Wmr; }
    else                 { wx = Wxh; wh = Whh; wm = Wmh; }
    if (col < 256)       src = wx + rr * 256 + col;
    else if (col < 1280) src = wh + (size_t)rr * 1024 + (col - 256);
    else                 src = wm + rr * 256 + (col - 1280);
    dst = (row < 2048) ? (WZR + (size_t)row * 1536 + col)
                       : (WH + (size_t)(row - 2048) * 1536 + col);
  } else {
    int t2 = t - 589824;
    src = Wgh + t2 * 8;
    dst = WGH + t2 * 8;
  }
  f32x4 a = *(const f32x4*)src;
  f32x4 b = *(const f32x4*)(src + 4);
  u16x8 v;
#pragma unroll
  for (int j = 0; j < 4; ++j) { v[j] = f2b(a[j]); v[j + 4] = f2b(b[j]); }
  *(u16x8*)dst = v;
}

// ---------------------------------------------------------------------------
// Elementwise over [B,D]: gamma_x, imputation, x_hat -> X1/X2 cols 0..255 and
// 1280..1535 (m), bf16 delta copy, f32 x_last_obs_new.
// ---------------------------------------------------------------------------
__global__ __launch_bounds__(256) void elem_k(
    const float* __restrict__ x, const float* __restrict__ m, const float* __restrict__ delta,
    const float* __restrict__ xlo, const float* __restrict__ x_mean,
    const float* __restrict__ Wgx, const float* __restrict__ bgx,
    u16* __restrict__ X1, u16* __restrict__ X2, u16* __restrict__ Dbf,
    float* __restrict__ out_xlo)
{
  int t = blockIdx.x * 256 + threadIdx.x;
  int row = t >> 5;
  int col = (t & 31) * 8;
  size_t base = (size_t)row * 256 + col;
  u16x8 vxhat, vm16, vd16;
  f32x4 vlnew[2];
#pragma unroll
  for (int half = 0; half < 2; ++half) {
    f32x4 vx = *(const f32x4*)(x + base + half * 4);
    f32x4 vm = *(const f32x4*)(m + base + half * 4);
    f32x4 vd = *(const f32x4*)(delta + base + half * 4);
    f32x4 vl = *(const f32x4*)(xlo + base + half * 4);
    f32x4 vmean = *(const f32x4*)(x_mean + col + half * 4);
    f32x4 vwg = *(const f32x4*)(Wgx + col + half * 4);
    f32x4 vbg = *(const f32x4*)(bgx + col + half * 4);
#pragma unroll
    for (int j = 0; j < 4; ++j) {
      float mf = vm[j];
      float lnew = (mf > 0.5f) ? vx[j] : vl[j];
      vlnew[half][j] = lnew;
      float gx = __expf(-fmaxf(vd[j] * vwg[j] + vbg[j], 0.0f));
      float ximp = gx * lnew + (1.0f - gx) * vmean[j];
      float xhat = mf * vx[j] + (1.0f - mf) * ximp;
      vxhat[half * 4 + j] = f2b(xhat);
      vm16[half * 4 + j] = f2b(mf);
      vd16[half * 4 + j] = f2b(vd[j]);
    }
  }
  size_t r1536 = (size_t)row * 1536;
  *(u16x8*)(X1 + r1536 + col) = vxhat;
  *(u16x8*)(X2 + r1536 + col) = vxhat;
  *(u16x8*)(X1 + r1536 + 1280 + col) = vm16;
  *(u16x8*)(X2 + r1536 + 1280 + col) = vm16;
  *(u16x8*)(Dbf + base) = vd16;
  *(f32x4*)(out_xlo + base) = vlnew[0];
  *(f32x4*)(out_xlo + base + 4) = vlnew[1];
}

// ---------------------------------------------------------------------------
// GEMM-B ONLY: 256x128-tile, 8 waves (4Mx2N), per-wave 64x64 (acc 4x4),
// ring-3 of BK=32 k-half slots, 72KB LDS -> 2 blocks/CU (4 waves/SIMD).
// LDS traffic per FLOP = 1/32 (read) + 1/85 (DMA write) = 0.0352 B/F,
// 1.78x less than r7's 0.0625 -> attacks the measured 60 B/cy LDS-pipe wall.
// Phase u: { ds_read 8 frags (slot u%3) ; STAGE unit u+2 -> slot (u+2)%3
//   (2 A-loads + 1 B-load per thread) ; vmcnt(3)+lgkm0 (PRE-barrier: retires
//   this slot's reads AND drains unit u+1 staged at u-1) ; BAR (publishes
//   unit u+1 for phase u+1; certifies slot (u+2)%3 dead for the restage
//   issued next phase) ; 16 MFMA }.
// Race ledger: reads of slot s (phase u) retire at u's lgkm0 PRE-BAR(u);
//   restage of s issued at phase u+1 POST-BAR(u) -> ordered. Unit u+1
//   drained by every wave's vmcnt(3) pre-BAR(u) -> landed before any wave's
//   phase-u+1 reads. Tail: clamped dummy stages keep vmcnt uniform; final
//   vmcnt(0) drains before epilogue/endpgm. Full 48-phase unroll: all slot
//   offsets literal, zero steady-state VALU addressing.
// Swizzle (0-conflict r2-r7): 16B chunk ^= (row>>1)&3, linear LDS dest +
//   inverse-swizzled global src + swizzled ds_read. XCD-bijective map.
// Epilogue EPI1: cols<1024: z=sigmoid -> Z ; cols>=1024: r*hdec -> X2.
// ---------------------------------------------------------------------------
__global__ __launch_bounds__(512, 4) void gemm_b256(
    const u16* __restrict__ A, const u16* __restrict__ W,
    const float* __restrict__ bz, const float* __restrict__ br,
    const u16* __restrict__ X1h, u16* __restrict__ Z, u16* __restrict__ X2)
{
  constexpr int K = 1536, P = 48;
  __shared__ alignas(16) u16 As[3][8192];   // 256 rows x 32 k  (16KB/slot)
  __shared__ alignas(16) u16 Bs[3][4096];   // 128 rows x 32 k  ( 8KB/slot)

  const int tid = threadIdx.x, lane = tid & 63, wave = tid >> 6;
  const int wr = wave >> 1, wc = wave & 1;        // 4M x 2N
  const int d = blockIdx.x;                       // nwg = 512
  const int L = (d & 7) * 64 + (d >> 3);          // bijective XCD map
  const int brow = (L >> 4) * 256, bcol = (L & 15) * 128;
  const int lr = lane & 15, g4 = lane >> 4;
  const int rc = (g4 ^ ((lr >> 1) & 3)) * 8;      // swizzled read chunk
  const int srow = tid >> 2;                      // staging row 0..127
  const int scs = ((tid & 3) ^ ((srow >> 1) & 3)) * 8;

  f32x4 acc[4][4];
#pragma unroll
  for (int i = 0; i < 4; ++i)
#pragma unroll
    for (int j = 0; j < 4; ++j) { f32x4 z0 = {0.f, 0.f, 0.f, 0.f}; acc[i][j] = z0; }

  const u16* aP = A + (size_t)(brow + srow) * K + scs;
  const u16* aQ = aP + (size_t)128 * K;           // rows 128..255
  const u16* bP = W + (size_t)(bcol + srow) * K + scs;
  u16* dA = &As[0][0] + tid * 8;                  // lane-linear glds dest
  u16* dB = &Bs[0][0] + tid * 8;
  const u16* rA = &As[0][0] + (wr * 64 + lr) * 32 + rc;
  const u16* rB = &Bs[0][0] + (wc * 64 + lr) * 32 + rc;

  auto STAGE = [&](int slot, int ko) {
    __builtin_amdgcn_global_load_lds(GPTR(aP + ko), LPTR(dA + slot * 8192), 16, 0, 0);
    __builtin_amdgcn_global_load_lds(GPTR(aQ + ko), LPTR(dA + slot * 8192 + 4096), 16, 0, 0);
    __builtin_amdgcn_global_load_lds(GPTR(bP + ko), LPTR(dB + slot * 4096), 16, 0, 0);
  };

  // prologue: units 0,1 -> slots 0,1; drain unit 0; publish
  STAGE(0, 0);
  STAGE(1, 32);
  asm volatile("s_waitcnt vmcnt(3)" ::: "memory");
  BAR;

#pragma unroll
  for (int u = 0; u < P; ++u) {
    const int sR = u % 3;
    const int sS = (u + 2) % 3;
    const int ko = ((u + 2 < P) ? (u + 2) : (P - 1)) * 32;  // tail: dummy
    s16x8 af[4], bf[4];
#pragma unroll
    for (int i = 0; i < 4; ++i) af[i] = *(const s16x8*)(rA + sR * 8192 + i * 512);
#pragma unroll
    for (int j = 0; j < 4; ++j) bf[j] = *(const s16x8*)(rB + sR * 4096 + j * 512);
    STAGE(sS, ko);
    SCHEDB;
    asm volatile("s_waitcnt vmcnt(3) lgkmcnt(0)" ::: "memory");
    SCHEDB;
    BAR;
    SETP1;
#pragma unroll
    for (int i = 0; i < 4; ++i)
#pragma unroll
      for (int j = 0; j < 4; ++j)
        acc[i][j] = __builtin_amdgcn_mfma_f32_16x16x32_bf16(af[i], bf[j], acc[i][j], 0, 0, 0);
    SETP0;
  }
  asm volatile("s_waitcnt vmcnt(0)" ::: "memory");  // drain dummy stages

  // epilogue: C/D layout col=lane&15, row=(lane>>4)*4+q  [verified m89/m91]
  const int row0 = brow + wr * 64 + g4 * 4;
  const int col0 = bcol + wc * 64 + lr;
#pragma unroll
  for (int i = 0; i < 4; ++i) {
#pragma unroll
    for (int j = 0; j < 4; ++j) {
      int c_ = col0 + j * 16;
#pragma unroll
      for (int qq = 0; qq < 4; ++qq) {
        int r_ = row0 + i * 16 + qq;
        float v = acc[i][j][qq];
        if (c_ < 1024) {
          Z[(size_t)r_ * 1024 + c_] = f2b(sigm(v + bz[c_]));
        } else {
          int jc = c_ - 1024;
          float rg = sigm(v + br[jc]);
          float hd = b2f(X1h[(size_t)r_ * 1536 + 256 + jc]);
          X2[(size_t)r_ * 1536 + 256 + jc] = f2b(rg * hd);
        }
      }
    }
  }
}

// ---------------------------------------------------------------------------
// GEMM A/C (r7 kernel, unchanged): 128x128-tile, 8 waves x 512thr, 2 blk/CU,
// per-wave 64x32, 4-slot ring, counted vmcnt(2). Known-good controls.
// EPI 0: h_decayed = exp(-relu(.+bgh)) * h      -> X1 cols 256..1279 (bf16)
// EPI 2: h_new = (1-z)*hdec + z*tanh(.+bmh)     -> d_out (f32); A = X2
// ---------------------------------------------------------------------------
template<int EPI, int GXL>
__global__ __launch_bounds__(512, 4) void gemm_bt(
    const u16* __restrict__ A, int K, const u16* __restrict__ W,
    const float* __restrict__ bias0, const float* __restrict__ bias1,
    const float* __restrict__ auxf,  // EPI0: h (f32)
    const u16* __restrict__ auxb,    // EPI2: X1 (hdec source, bf16)
    const u16* __restrict__ aux2b,   // EPI2: Z (bf16)
    u16* __restrict__ out0b,         // EPI0: X1
    float* __restrict__ outf)        // EPI2: d_out h_new
{
  constexpr int GX = 1 << GXL;
  constexpr int SL = 128 * 32;
  __shared__ alignas(16) u16 As[4][SL];
  __shared__ alignas(16) u16 Bs[4][SL];

  const int tid = threadIdx.x;
  const int lane = tid & 63;
  const int wave = tid >> 6;
  const int wr = wave >> 2, wc = wave & 3;

  const int d = blockIdx.x;
  const int q = (int)gridDim.x >> 3;
  const int L = (d & 7) * q + (d >> 3);
  const int brow = (L >> GXL) * 128;
  const int bcol = (L & (GX - 1)) * 128;
  const int NT = K / 64;

  const int lr = lane & 15, g4 = lane >> 4;
  const int rc = (g4 ^ ((lr >> 1) & 3)) * 8;
  const int srow = lane >> 2;
  const int scs = ((lane & 3) ^ ((srow >> 1) & 3)) * 8;

  f32x4 acc[4][2];
#pragma unroll
  for (int i = 0; i < 4; ++i)
#pragma unroll
    for (int j = 0; j < 2; ++j) { f32x4 z0 = {0.f, 0.f, 0.f, 0.f}; acc[i][j] = z0; }

  const u16* aP = A + (size_t)(brow + wave * 16 + srow) * K + scs;
  const u16* bP = W + (size_t)(bcol + wave * 16 + srow) * K + scs;
  u16* ldsA = &As[0][0] + wave * 512;
  u16* ldsB = &Bs[0][0] + wave * 512;
  const u16* rdA = &As[0][0] + (wr * 64 + lr) * 32 + rc;
  const u16* rdB = &Bs[0][0] + (wc * 32 + lr) * 32 + rc;

  auto STAGE = [&](int slot, int koff) {
    __builtin_amdgcn_global_load_lds(GPTR(aP + koff), LPTR(ldsA + slot * SL), 16, 0, 0);
    __builtin_amdgcn_global_load_lds(GPTR(bP + koff), LPTR(ldsB + slot * SL), 16, 0, 0);
  };

  auto PHASE = [&](int slotR, int slotS, int koff, int stg, int vm) {
    s16x8 af[4], bf[2];
    const u16* pA = rdA + slotR * SL;
    const u16* pB = rdB + slotR * SL;
#pragma unroll
    for (int i = 0; i < 4; ++i) af[i] = *(const s16x8*)(pA + i * 512);
#pragma unroll
    for (int j = 0; j < 2; ++j) bf[j] = *(const s16x8*)(pB + j * 512);
    if (stg) STAGE(slotS, koff);
    SCHEDB;
    if (vm == 2) asm volatile("s_waitcnt vmcnt(2)" ::: "memory");
    else if (vm == 0) asm volatile("s_waitcnt vmcnt(0)" ::: "memory");
    BAR;
    asm volatile("s_waitcnt lgkmcnt(0)" ::: "memory");
    SCHEDB;
    SETP1;
#pragma unroll
    for (int i = 0; i < 4; ++i)
#pragma unroll
      for (int j = 0; j < 2; ++j)
        acc[i][j] = __builtin_amdgcn_mfma_f32_16x16x32_bf16(af[i], bf[j], acc[i][j], 0, 0, 0);
    SETP0;
  };

  STAGE(0, 0);
  STAGE(1, 32);
  asm volatile("s_waitcnt vmcnt(2)" ::: "memory");
  BAR;

  for (int kt = 0; kt < NT - 2; kt += 2) {
    PHASE(0, 2, 64, 1, 2);
    PHASE(1, 3, 96, 1, 2);
    PHASE(2, 0, 128, 1, 2);
    PHASE(3, 1, 160, 1, 2);
    aP += 128; bP += 128;
  }
  PHASE(0, 2, 64, 1, 2);
  PHASE(1, 3, 96, 1, 2);
  PHASE(2, 0, 0, 0, 0);
  PHASE(3, 0, 0, 0, -1);

  const int row0 = brow + wr * 64 + g4 * 4;
  const int col0 = bcol + wc * 32 + lr;
#pragma unroll
  for (int i = 0; i < 4; ++i) {
#pragma unroll
    for (int j = 0; j < 2; ++j) {
      int c_ = col0 + j * 16;
#pragma unroll
      for (int qq = 0; qq < 4; ++qq) {
        int r_ = row0 + i * 16 + qq;
        float v = acc[i][j][qq];
        if constexpr (EPI == 0) {
          float p = v + bias0[c_];
          float gh = __expf(-fmaxf(p, 0.0f));
          float hd = gh * auxf[(size_t)r_ * 1024 + c_];
          out0b[(size_t)r_ * 1536 + 256 + c_] = f2b(hd);
        } else {
          float ht = tanhf(v + bias0[c_]);
          float zz = b2f(aux2b[(size_t)r_ * 1024 + c_]);
          float hd = b2f(auxb[(size_t)r_ * 1536 + 256 + c_]);
          outf[(size_t)r_ * 1024 + c_] = (1.0f - zz) * hd + zz * ht;
        }
      }
    }
  }
}

// ---------------------------------------------------------------------------
extern "C" void kernel_launch(void* const* d_in, const int* in_sizes, int n_in,
                              void* d_out, int out_size, void* d_ws, size_t ws_size,
                              hipStream_t stream)
{
  const float* x     = (const float*)d_in[0];
  const float* m     = (const float*)d_in[1];
  const float* delta = (const float*)d_in[2];
  const float* h     = (const float*)d_in[3];
  const float* xlo   = (const float*)d_in[4];
  const float* xmean = (const float*)d_in[5];
  const float* Wgx   = (const float*)d_in[6];
  const float* bgx   = (const float*)d_in[7];
  const float* Wgh   = (const float*)d_in[8];
  const float* bgh   = (const float*)d_in[9];
  const float* Wxz   = (const float*)d_in[10];
  const float* Whz   = (const float*)d_in[11];
  const float* Wmz   = (const float*)d_in[12];
  const float* bmz   = (const float*)d_in[13];
  const float* Wxr   = (const float*)d_in[14];
  const float* Whr   = (const float*)d_in[15];
  const float* Wmr   = (const float*)d_in[16];
  const float* bmr   = (const float*)d_in[17];
  const float* Wxh   = (const float*)d_in[18];
  const float* Whh   = (const float*)d_in[19];
  const float* Wmh   = (const float*)d_in[20];
  const float* bmh   = (const float*)d_in[21];

  // workspace (bf16): X1[8192,1536] X2[8192,1536] Z[8192,1024]
  //   WZR[2048,1536] WH[1024,1536] Dbf[8192,256] WGH[1024,256]  ~81.3MB
  u16* X1  = (u16*)d_ws;
  u16* X2  = X1 + (size_t)8192 * 1536;
  u16* Z   = X2 + (size_t)8192 * 1536;
  u16* WZR = Z  + (size_t)8192 * 1024;
  u16* WH  = WZR + (size_t)2048 * 1536;
  u16* Dbf = WH + (size_t)1024 * 1536;
  u16* WGH = Dbf + (size_t)8192 * 256;

  float* out_h   = (float*)d_out;
  float* out_xlo = out_h + (size_t)8192 * 1024;

  pack_w<<<2432, 256, 0, stream>>>(Wxz, Whz, Wmz, Wxr, Whr, Wmr, Wxh, Whh, Wmh, Wgh, WZR, WH, WGH);
  elem_k<<<1024, 256, 0, stream>>>(x, m, delta, xlo, xmean, Wgx, bgx, X1, X2, Dbf, out_xlo);
  // GEMM A: gamma_h -> h_decayed into X1[:,256:1280]   (M=8192,N=1024,K=256)
  gemm_bt<0, 3><<<512, 512, 0, stream>>>(
      Dbf, 256, WGH, bgh, nullptr, h, nullptr, nullptr, X1, nullptr);
  // GEMM B: z -> Z ; r*h_decayed -> X2[:,256:1280]     (M=8192,N=2048,K=1536)
  gemm_b256<<<512, 512, 0, stream>>>(X1, WZR, bmz, bmr, X1, Z, X2);
  // GEMM C: h_tilde + final blend -> h_new (f32)       (M=8192,N=1024,K=1536)
  gemm_bt<2, 3><<<512, 512, 0, stream>>>(
      X2, 1536, WH, bmh, nullptr, nullptr, X1, Z, nullptr, out_h);
}